// Round 12
// baseline (5974.427 us; speedup 1.0000x reference)
//
#include <hip/hip_runtime.h>
#include <hip/hip_bf16.h>

#define L_SIZE 80000
#define C_SIZE 120000
#define N_EDGES 480000
#define DIM 128
#define GDIM 512
#define N_ITER 8
#define MAXDEG 64   // ELL width; Poisson(4)/Poisson(6) max over 120k rows << 64

typedef __attribute__((ext_vector_type(8))) short short8;   // 8 bf16 (4 VGPR) MFMA frag
typedef __attribute__((ext_vector_type(4))) short short4v;  // 4 bf16 (8B store)
typedef __attribute__((ext_vector_type(4))) float f32x4;    // MFMA acc frag

__device__ __forceinline__ ushort f2bf(float f) {           // fp32 -> bf16 RNE
    uint u = __float_as_uint(f);
    u = u + 0x7FFFu + ((u >> 16) & 1u);
    return (ushort)(u >> 16);
}
__device__ __forceinline__ float bf2f(ushort h) {
    return __uint_as_float(((uint)h) << 16);
}
// Truncation split: v = bf2f(hi)+bf2f(lo)+err, |err| <= 2^-16 |v| (4 VALU ops).
__device__ __forceinline__ void split2(float f, short& hi, short& lo) {
    uint u = __float_as_uint(f);
    hi = (short)(u >> 16);
    float r = f - __uint_as_float(u & 0xFFFF0000u);
    lo = (short)(__float_as_uint(r) >> 16);
}
__device__ __forceinline__ float sigmf(float x) { return 1.f / (1.f + __expf(-x)); }
__device__ __forceinline__ float tanh_f(float x) {
    float e = __expf(2.f * x);
    return 1.f - 2.f / (e + 1.f);
}
__device__ __forceinline__ f32x4 fzero4() {
    f32x4 v; v[0] = v[1] = v[2] = v[3] = 0.f; return v;
}

// ---------------------------------------------------------------------------
// ELL build: one atomic pass. cnt and ell must be zeroed.
// ---------------------------------------------------------------------------
__global__ __launch_bounds__(256) void fill_ell(
    const int* __restrict__ src, const int* __restrict__ dst,
    int* __restrict__ cnt, int* __restrict__ ell)
{
    int i = blockIdx.x * 256 + threadIdx.x;   // grid sized exactly N_EDGES/256
    int d = dst[i];
    int pos = atomicAdd(&cnt[d], 1);
    ell[(size_t)d * MAXDEG + pos] = src[i];
}

// ---------------------------------------------------------------------------
// Pack fp32 W[K,N] -> split-bf16 fragment-layout planes Ph, Pl (RNE; one-time).
// element = W[ks*32 + hi*8 + j][cc*16 + c], flat (((ks*NC+cc)*16+c)*4+hi)*8+j
// ---------------------------------------------------------------------------
__global__ __launch_bounds__(256) void pack_w2(const float* __restrict__ W,
                                               ushort* __restrict__ Ph,
                                               ushort* __restrict__ Pl, int K, int N)
{
    int NC = N / 16;
    int total = K * N;
    for (int o = blockIdx.x * 256 + threadIdx.x; o < total; o += gridDim.x * 256) {
        int j = o & 7, hi = (o >> 3) & 3, c = (o >> 5) & 15;
        int rest = o >> 9;
        int cc = rest % NC, ks = rest / NC;
        int row = ks * 32 + hi * 8 + j, col = cc * 16 + c;
        float v = W[(size_t)row * N + col];
        ushort h = f2bf(v);
        Ph[o] = h;
        Pl[o] = f2bf(v - bf2f(h));
    }
}

// ---------------------------------------------------------------------------
// Stage fp32 [nrows,128] rows into LDS as split-bf16 (hi plane at dst, lo at
// dst + nrows*128 elems). Row stride 256B, XOR-swizzled byte ^= (row&7)<<4.
// ---------------------------------------------------------------------------
__device__ __forceinline__ void stageA2(const float* __restrict__ src, int rowBase,
                                        ushort* dst, int tid, int nrows)
{
    const int planeB = nrows * 256;
    for (int idx = tid * 8; idx < nrows * 128; idx += 512 * 8) {
        int r = idx >> 7, k8 = idx & 127;
        const float* p = src + (size_t)(rowBase + r) * DIM + k8;
        float4 v0 = *(const float4*)p;
        float4 v1 = *(const float4*)(p + 4);
        float f[8] = {v0.x, v0.y, v0.z, v0.w, v1.x, v1.y, v1.z, v1.w};
        short8 hi8, lo8;
        #pragma unroll
        for (int j = 0; j < 8; ++j) {
            short h, l;
            split2(f[j], h, l);
            hi8[j] = h;
            lo8[j] = l;
        }
        int boff = r * 256 + ((k8 * 2) ^ ((r & 7) << 4));
        *(short8*)((char*)dst + boff) = hi8;
        *(short8*)((char*)dst + planeB + boff) = lo8;
    }
}

// A-frag: a[j] = A[mi*16 + (lane&15)][k0 + (lane>>4)*8 + j]  (swizzled LDS)
__device__ __forceinline__ short8 readA(const ushort* As, int mi, int k0, int lane)
{
    int r = mi * 16 + (lane & 15);
    int kb = (k0 * 2 + ((lane >> 4) << 4)) ^ ((r & 7) << 4);
    return *(const short8*)((const char*)As + r * 256 + kb);
}

// A-frag with row^1 (literal flip): tile row r of X1 == tile row r^1 of H.
__device__ __forceinline__ short8 readAf(const ushort* As, int mi, int k0, int lane)
{
    int r = (mi * 16 + (lane & 15)) ^ 1;
    int kb = (k0 * 2 + ((lane >> 4) << 4)) ^ ((r & 7) << 4);
    return *(const short8*)((const char*)As + r * 256 + kb);
}

__device__ __forceinline__ short8 readB(const ushort* P, int ks, int NC, int cc,
                                        int laneOff)
{
    return *(const short8*)((const char*)P + (((size_t)(ks * NC + cc)) << 10) + laneOff);
}

// 3-term split-bf16 MFMA: acc += (ah+al)(bh+bl), dropping lo*lo
#define MFMA3(acc, ah, al, bh, bl)                                              \
    acc = __builtin_amdgcn_mfma_f32_16x16x32_bf16(ah, bh, acc, 0, 0, 0);        \
    acc = __builtin_amdgcn_mfma_f32_16x16x32_bf16(ah, bl, acc, 0, 0, 0);        \
    acc = __builtin_amdgcn_mfma_f32_16x16x32_bf16(al, bh, acc, 0, 0, 0);

// ---------------------------------------------------------------------------
// Fused 2-layer MLP: msg = relu(A@W1+b1)@W2+b2 (fp32 out). 32 rows/block,
// 512 thr (8 waves); wave wv owns output cols [16wv,16wv+16). Hidden in LDS
// as split-bf16. 32-row tile: LDS 32KB, low VGPR -> (512,6) = 24 waves/CU.
// ---------------------------------------------------------------------------
__global__ __launch_bounds__(512, 6) void mlp_kernel(
    const float* __restrict__ A,
    const ushort* __restrict__ w1Ph, const ushort* __restrict__ w1Pl,
    const float* __restrict__ b1,
    const ushort* __restrict__ w2Ph, const ushort* __restrict__ w2Pl,
    const float* __restrict__ b2,
    float* __restrict__ msg)
{
    __shared__ __align__(16) ushort AsIn[2 * 32 * 128];
    __shared__ __align__(16) ushort AsHid[2 * 32 * 128];
    const int tid = threadIdx.x;
    const int wv = tid >> 6, lane = tid & 63;
    const int cl = lane & 15, hi = lane >> 4;
    const int rowBase = blockIdx.x * 32;
    const int laneOff = (cl * 4 + hi) * 16;
    const int col = wv * 16 + cl;

    stageA2(A, rowBase, AsIn, tid, 32);
    __syncthreads();

    f32x4 acc[2];
    acc[0] = fzero4(); acc[1] = fzero4();
    #pragma unroll
    for (int ks = 0; ks < 4; ++ks) {
        short8 bh = readB(w1Ph, ks, 8, wv, laneOff);
        short8 bl = readB(w1Pl, ks, 8, wv, laneOff);
        #pragma unroll
        for (int mi = 0; mi < 2; ++mi) {
            short8 ah = readA(AsIn, mi, ks * 32, lane);
            short8 al = readA(AsIn + 32 * 128, mi, ks * 32, lane);
            MFMA3(acc[mi], ah, al, bh, bl);
        }
    }
    float b1c = b1[col];
    #pragma unroll
    for (int mi = 0; mi < 2; ++mi)
        #pragma unroll
        for (int q = 0; q < 4; ++q) {
            int row = mi * 16 + hi * 4 + q;
            float v = fmaxf(acc[mi][q] + b1c, 0.f);
            short h2, l2;
            split2(v, h2, l2);
            int boff = row * 256 + ((2 * col) ^ ((row & 7) << 4));
            *(short*)((char*)AsHid + boff) = h2;
            *(short*)((char*)AsHid + 32 * 256 + boff) = l2;
        }
    __syncthreads();

    f32x4 acc2[2];
    acc2[0] = fzero4(); acc2[1] = fzero4();
    #pragma unroll
    for (int ks = 0; ks < 4; ++ks) {
        short8 bh = readB(w2Ph, ks, 8, wv, laneOff);
        short8 bl = readB(w2Pl, ks, 8, wv, laneOff);
        #pragma unroll
        for (int mi = 0; mi < 2; ++mi) {
            short8 ah = readA(AsHid, mi, ks * 32, lane);
            short8 al = readA(AsHid + 32 * 128, mi, ks * 32, lane);
            MFMA3(acc2[mi], ah, al, bh, bl);
        }
    }
    float b2c = b2[col];
    #pragma unroll
    for (int mi = 0; mi < 2; ++mi)
        #pragma unroll
        for (int q = 0; q < 4; ++q) {
            int row = mi * 16 + hi * 4 + q;
            msg[(size_t)(rowBase + row) * DIM + col] = acc2[mi][q] + b2c;
        }
}

// ---------------------------------------------------------------------------
// Fused ELL-gather + LN-LSTM cell. 16 rows/block, 512 threads = 8 waves.
// 16-row tile halves accumulators (32 VGPR) -> (512,6) targets <=85 VGPR =
// 3 blocks/CU = 24 waves/CU (was 16). Wave wv owns gate cols {128jb+16wv+cl}.
// X1 (literal flip) read from AsH with row^1 (rowBase even, pairs in-tile).
// ---------------------------------------------------------------------------
template<int KX>   // 4 = clause, 8 = literal
__global__ __launch_bounds__(512, 6) void lstm_kernel(
    const float* __restrict__ msg, const int* __restrict__ cnt,
    const int* __restrict__ ell,
    const float* __restrict__ Hsrc,
    const ushort* __restrict__ wiPh, const ushort* __restrict__ wiPl,
    const ushort* __restrict__ whPh, const ushort* __restrict__ whPl,
    const float* __restrict__ g_ih, const float* __restrict__ b_ih,
    const float* __restrict__ g_hh, const float* __restrict__ b_hh,
    const float* __restrict__ g_c,  const float* __restrict__ b_c,
    float* __restrict__ c_state, float* __restrict__ h_out)
{
    __shared__ __align__(16) ushort AsX0[2 * 16 * 128];   // 8 KB
    __shared__ __align__(16) ushort AsH [2 * 16 * 128];   // 8 KB
    __shared__ float red4f[16 * 33];   // odd stride: conflict-free
    __shared__ float lnstf[16 * 4];
    __shared__ float red2f[16 * 17];
    __shared__ float lncf[16 * 2];

    const int tid = threadIdx.x;
    const int wv = tid >> 6, lane = tid & 63;
    const int cl = lane & 15, hi = lane >> 4;
    const int rowBase = blockIdx.x * 16;
    const int laneOff = (cl * 4 + hi) * 16;
    const int d = wv * 16 + cl;

    // linear stage first: static loads fire and overlap the gather below
    stageA2(Hsrc, rowBase, AsH, tid, 16);

    // ---- ELL gather -> X0 (32 threads/row, 4 dims each), 4-edge unrolled ----
    {
        int r = tid >> 5;                  // 0..15
        int d4 = (tid & 31) << 2;          // 0..124
        int row = rowBase + r;
        int deg = cnt[row];
        const int* sl = ell + (size_t)row * MAXDEG;
        float a0 = 0.f, a1 = 0.f, a2 = 0.f, a3 = 0.f;
        for (int k = 0; k < deg; k += 4) {
            int i0 = sl[k], i1 = sl[k+1], i2 = sl[k+2], i3 = sl[k+3];
            float4 p0 = *(const float4*)(msg + (size_t)i0 * DIM + d4);
            float4 p1 = *(const float4*)(msg + (size_t)i1 * DIM + d4);
            float4 p2 = *(const float4*)(msg + (size_t)i2 * DIM + d4);
            float4 p3 = *(const float4*)(msg + (size_t)i3 * DIM + d4);
            float w1 = (k + 1 < deg) ? 1.f : 0.f;
            float w2 = (k + 2 < deg) ? 1.f : 0.f;
            float w3 = (k + 3 < deg) ? 1.f : 0.f;
            a0 += p0.x;      a1 += p0.y;      a2 += p0.z;      a3 += p0.w;
            a0 += w1 * p1.x; a1 += w1 * p1.y; a2 += w1 * p1.z; a3 += w1 * p1.w;
            a0 += w2 * p2.x; a1 += w2 * p2.y; a2 += w2 * p2.z; a3 += w2 * p2.w;
            a0 += w3 * p3.x; a1 += w3 * p3.y; a2 += w3 * p3.z; a3 += w3 * p3.w;
        }
        float f[4] = {a0, a1, a2, a3};
        short4v hi4, lo4;
        #pragma unroll
        for (int j = 0; j < 4; ++j) {
            short h, l;
            split2(f[j], h, l);
            hi4[j] = h;
            lo4[j] = l;
        }
        int boff = r * 256 + ((d4 * 2) ^ ((r & 7) << 4));
        *(short4v*)((char*)AsX0 + boff) = hi4;
        *(short4v*)((char*)AsX0 + 16 * 256 + boff) = lo4;
    }
    __syncthreads();

    f32x4 xacc[4], hacc[4];
    #pragma unroll
    for (int jb = 0; jb < 4; ++jb) { xacc[jb] = fzero4(); hacc[jb] = fzero4(); }

    #pragma unroll
    for (int ks = 0; ks < KX; ++ks) {
        int k0 = (ks & 3) * 32;
        short8 axh, axl;
        if (KX == 8 && ks >= 4) {   // X1 tile = flip rows of the H tile
            axh = readAf(AsH, 0, k0, lane);
            axl = readAf(AsH + 16 * 128, 0, k0, lane);
        } else {
            axh = readA(AsX0, 0, k0, lane);
            axl = readA(AsX0 + 16 * 128, 0, k0, lane);
        }
        #pragma unroll
        for (int jb = 0; jb < 4; ++jb) {
            short8 bh = readB(wiPh, ks, 32, jb * 8 + wv, laneOff);
            short8 bl = readB(wiPl, ks, 32, jb * 8 + wv, laneOff);
            MFMA3(xacc[jb], axh, axl, bh, bl);
        }
        if (ks < 4) {
            short8 ahh = readA(AsH, 0, k0, lane);
            short8 ahl = readA(AsH + 16 * 128, 0, k0, lane);
            #pragma unroll
            for (int jb = 0; jb < 4; ++jb) {
                short8 bh = readB(whPh, ks, 32, jb * 8 + wv, laneOff);
                short8 bl = readB(whPl, ks, 32, jb * 8 + wv, laneOff);
                MFMA3(hacc[jb], ahh, ahl, bh, bl);
            }
        }
    }

    // ---- LN(512) stats for X and H ----
    #pragma unroll
    for (int q = 0; q < 4; ++q) {
        float px = 0.f, pqx = 0.f, ph = 0.f, pqh = 0.f;
        #pragma unroll
        for (int jb = 0; jb < 4; ++jb) {
            float v = xacc[jb][q]; px += v; pqx += v * v;
            float u = hacc[jb][q]; ph += u; pqh += u * u;
        }
        #pragma unroll
        for (int m = 1; m < 16; m <<= 1) {
            px += __shfl_xor(px, m); pqx += __shfl_xor(pqx, m);
            ph += __shfl_xor(ph, m); pqh += __shfl_xor(pqh, m);
        }
        if (cl == 0) {
            int row = hi * 4 + q;
            float* rp = red4f + row * 33 + wv * 4;
            rp[0] = px; rp[1] = pqx; rp[2] = ph; rp[3] = pqh;
        }
    }
    __syncthreads();
    if (tid < 16) {
        float sx = 0.f, qx = 0.f, sh = 0.f, qh = 0.f;
        const float* rp = red4f + tid * 33;
        for (int ww = 0; ww < 8; ++ww) {
            sx += rp[ww * 4 + 0]; qx += rp[ww * 4 + 1];
            sh += rp[ww * 4 + 2]; qh += rp[ww * 4 + 3];
        }
        const float inv = 1.f / 512.f;
        float mux = sx * inv, muh = sh * inv;
        lnstf[tid * 4 + 0] = mux;
        lnstf[tid * 4 + 1] = rsqrtf(qx * inv - mux * mux + 1e-5f);
        lnstf[tid * 4 + 2] = muh;
        lnstf[tid * 4 + 3] = rsqrtf(qh * inv - muh * muh + 1e-5f);
    }
    __syncthreads();

    // gate params loaded here (short liveness, not across the MFMA loop)
    float gih[4], bih[4], ghh[4], bhh[4];
    #pragma unroll
    for (int jb = 0; jb < 4; ++jb) {
        int col = jb * 128 + d;
        gih[jb] = g_ih[col]; bih[jb] = b_ih[col];
        ghh[jb] = g_hh[col]; bhh[jb] = b_hh[col];
    }

    float cn[4], og[4];
    #pragma unroll
    for (int q = 0; q < 4; ++q) {
        int row = hi * 4 + q;
        float mux = lnstf[row * 4 + 0], rx = lnstf[row * 4 + 1];
        float muh = lnstf[row * 4 + 2], rh = lnstf[row * 4 + 3];
        float g4[4];
        #pragma unroll
        for (int jb = 0; jb < 4; ++jb)
            g4[jb] = (xacc[jb][q] - mux) * rx * gih[jb] + bih[jb]
                   + (hacc[jb][q] - muh) * rh * ghh[jb] + bhh[jb];
        float cp = c_state[(size_t)(rowBase + row) * DIM + d];
        float cv = sigmf(g4[1]) * cp + sigmf(g4[0]) * tanh_f(g4[2]);
        cn[q] = cv; og[q] = g4[3];
        float sc = cv, qc = cv * cv;
        #pragma unroll
        for (int m = 1; m < 16; m <<= 1) {
            sc += __shfl_xor(sc, m); qc += __shfl_xor(qc, m);
        }
        if (cl == 0) {
            float* rp = red2f + row * 17 + wv * 2;
            rp[0] = sc; rp[1] = qc;
        }
    }
    __syncthreads();
    if (tid < 16) {
        float sc = 0.f, qc = 0.f;
        const float* rp = red2f + tid * 17;
        for (int ww = 0; ww < 8; ++ww) { sc += rp[ww * 2]; qc += rp[ww * 2 + 1]; }
        const float inv = 1.f / 128.f;
        float mu = sc * inv;
        lncf[tid * 2 + 0] = mu;
        lncf[tid * 2 + 1] = rsqrtf(qc * inv - mu * mu + 1e-5f);
    }
    __syncthreads();

    const float gcv = g_c[d], bcv = b_c[d];
    #pragma unroll
    for (int q = 0; q < 4; ++q) {
        int row = hi * 4 + q;
        size_t go = (size_t)(rowBase + row) * DIM + d;
        float cv = cn[q];
        float hv = sigmf(og[q]) *
                   tanh_f((cv - lncf[row * 2]) * lncf[row * 2 + 1] * gcv + bcv);
        c_state[go] = cv;
        h_out[go] = hv;
    }
}

// ---------------------------------------------------------------------------
extern "C" void kernel_launch(void* const* d_in, const int* in_sizes, int n_in,
                              void* d_out, int out_size, void* d_ws, size_t ws_size,
                              hipStream_t stream)
{
    const int*   l_edge  = (const int*)d_in[2];
    const int*   c_edge  = (const int*)d_in[3];
    const float* l_emb0  = (const float*)d_in[4];
    const float* c_emb0  = (const float*)d_in[5];
    const float* l2c_w1  = (const float*)d_in[6];
    const float* l2c_b1  = (const float*)d_in[7];
    const float* l2c_w2  = (const float*)d_in[8];
    const float* l2c_b2  = (const float*)d_in[9];
    const float* c2l_w1  = (const float*)d_in[10];
    const float* c2l_b1  = (const float*)d_in[11];
    const float* c2l_w2  = (const float*)d_in[12];
    const float* c2l_b2  = (const float*)d_in[13];
    const float* cu_wi   = (const float*)d_in[14];
    const float* cu_wh   = (const float*)d_in[15];
    const float* cu_g_ih = (const float*)d_in[16];
    const float* cu_b_ih = (const float*)d_in[17];
    const float* cu_g_hh = (const float*)d_in[18];
    const float* cu_b_hh = (const float*)d_in[19];
    const float* cu_g_c  = (const float*)d_in[20];
    const float* cu_b_c  = (const float*)d_in[21];
    const float* lu_wi   = (const float*)d_in[22];
    const float* lu_wh   = (const float*)d_in[23];
    const float* lu_g_ih = (const float*)d_in[24];
    const float* lu_b_ih = (const float*)d_in[25];
    const float* lu_g_hh = (const float*)d_in[26];
    const float* lu_b_hh = (const float*)d_in[27];
    const float* lu_g_c  = (const float*)d_in[28];
    const float* lu_b_c  = (const float*)d_in[29];

    float* out = (float*)d_out;
    float* l_slab = out;                              // [9, L, 128]
    float* c_slab = out + (size_t)9 * L_SIZE * DIM;   // [9, C, 128]

    // ---- workspace (~216 MB; identical footprint to verified round 8) ----
    char* wp = (char*)d_ws;
    float*  l_state = (float*)wp;  wp += (size_t)L_SIZE * DIM * 4;
    float*  c_state = (float*)wp;  wp += (size_t)C_SIZE * DIM * 4;
    float*  msg     = (float*)wp;  wp += (size_t)C_SIZE * DIM * 4;
    int* c_cnt = (int*)wp; wp += C_SIZE * 4;
    int* l_cnt = (int*)wp; wp += L_SIZE * 4;
    int* c_ell = (int*)wp; wp += (size_t)C_SIZE * MAXDEG * 4;   // 30.7 MB
    int* l_ell = (int*)wp; wp += (size_t)L_SIZE * MAXDEG * 4;   // 20.5 MB
    ushort* l2c_w1Ph = (ushort*)wp; wp += 128 * 128 * 2;
    ushort* l2c_w1Pl = (ushort*)wp; wp += 128 * 128 * 2;
    ushort* l2c_w2Ph = (ushort*)wp; wp += 128 * 128 * 2;
    ushort* l2c_w2Pl = (ushort*)wp; wp += 128 * 128 * 2;
    ushort* c2l_w1Ph = (ushort*)wp; wp += 128 * 128 * 2;
    ushort* c2l_w1Pl = (ushort*)wp; wp += 128 * 128 * 2;
    ushort* c2l_w2Ph = (ushort*)wp; wp += 128 * 128 * 2;
    ushort* c2l_w2Pl = (ushort*)wp; wp += 128 * 128 * 2;
    ushort* cu_wiPh  = (ushort*)wp; wp += 128 * 512 * 2;
    ushort* cu_wiPl  = (ushort*)wp; wp += 128 * 512 * 2;
    ushort* cu_whPh  = (ushort*)wp; wp += 128 * 512 * 2;
    ushort* cu_whPl  = (ushort*)wp; wp += 128 * 512 * 2;
    ushort* lu_wiPh  = (ushort*)wp; wp += 256 * 512 * 2;
    ushort* lu_wiPl  = (ushort*)wp; wp += 256 * 512 * 2;
    ushort* lu_whPh  = (ushort*)wp; wp += 128 * 512 * 2;
    ushort* lu_whPl  = (ushort*)wp; wp += 128 * 512 * 2;

    const int eb = N_EDGES / 256;

    // ELL build
    hipMemsetAsync(c_cnt, 0, C_SIZE * 4, stream);
    hipMemsetAsync(l_cnt, 0, L_SIZE * 4, stream);
    hipMemsetAsync(c_ell, 0, (size_t)C_SIZE * MAXDEG * 4, stream);
    hipMemsetAsync(l_ell, 0, (size_t)L_SIZE * MAXDEG * 4, stream);
    fill_ell<<<eb, 256, 0, stream>>>(l_edge, c_edge, c_cnt, c_ell);
    fill_ell<<<eb, 256, 0, stream>>>(c_edge, l_edge, l_cnt, l_ell);

    // pack weights to split-bf16 fragment layout
    pack_w2<<<64, 256, 0, stream>>>(l2c_w1, l2c_w1Ph, l2c_w1Pl, 128, 128);
    pack_w2<<<64, 256, 0, stream>>>(l2c_w2, l2c_w2Ph, l2c_w2Pl, 128, 128);
    pack_w2<<<64, 256, 0, stream>>>(c2l_w1, c2l_w1Ph, c2l_w1Pl, 128, 128);
    pack_w2<<<64, 256, 0, stream>>>(c2l_w2, c2l_w2Ph, c2l_w2Pl, 128, 128);
    pack_w2<<<256, 256, 0, stream>>>(cu_wi, cu_wiPh, cu_wiPl, 128, 512);
    pack_w2<<<256, 256, 0, stream>>>(cu_wh, cu_whPh, cu_whPl, 128, 512);
    pack_w2<<<512, 256, 0, stream>>>(lu_wi, lu_wiPh, lu_wiPl, 256, 512);
    pack_w2<<<256, 256, 0, stream>>>(lu_wh, lu_whPh, lu_whPl, 128, 512);

    hipMemcpyAsync(l_slab, l_emb0, (size_t)L_SIZE * DIM * sizeof(float),
                   hipMemcpyDeviceToDevice, stream);
    hipMemcpyAsync(c_slab, c_emb0, (size_t)C_SIZE * DIM * sizeof(float),
                   hipMemcpyDeviceToDevice, stream);
    hipMemsetAsync(l_state, 0, (size_t)L_SIZE * DIM * sizeof(float), stream);
    hipMemsetAsync(c_state, 0, (size_t)C_SIZE * DIM * sizeof(float), stream);

    for (int t = 0; t < N_ITER; ++t) {
        const float* le = l_slab + (size_t)t * L_SIZE * DIM;
        const float* ce = c_slab + (size_t)t * C_SIZE * DIM;
        float* le1 = l_slab + (size_t)(t + 1) * L_SIZE * DIM;
        float* ce1 = c_slab + (size_t)(t + 1) * C_SIZE * DIM;

        // ---- literal -> clause ----
        mlp_kernel<<<L_SIZE / 32, 512, 0, stream>>>(le, l2c_w1Ph, l2c_w1Pl, l2c_b1,
                                                    l2c_w2Ph, l2c_w2Pl, l2c_b2, msg);
        lstm_kernel<4><<<C_SIZE / 16, 512, 0, stream>>>(
            msg, c_cnt, c_ell, ce,
            cu_wiPh, cu_wiPl, cu_whPh, cu_whPl,
            cu_g_ih, cu_b_ih, cu_g_hh, cu_b_hh, cu_g_c, cu_b_c,
            c_state, ce1);

        // ---- clause -> literal ----
        mlp_kernel<<<C_SIZE / 32, 512, 0, stream>>>(ce1, c2l_w1Ph, c2l_w1Pl, c2l_b1,
                                                    c2l_w2Ph, c2l_w2Pl, c2l_b2, msg);
        lstm_kernel<8><<<L_SIZE / 16, 512, 0, stream>>>(
            msg, l_cnt, l_ell, le,
            lu_wiPh, lu_wiPl, lu_whPh, lu_whPl,
            lu_g_ih, lu_b_ih, lu_g_hh, lu_b_hh, lu_g_c, lu_b_c,
            l_state, le1);
    }
}

// Round 14
// 5330.639 us; speedup vs baseline: 1.1208x; 1.1208x over previous
//
#include <hip/hip_runtime.h>
#include <hip/hip_bf16.h>

#define L_SIZE 80000
#define C_SIZE 120000
#define N_EDGES 480000
#define DIM 128
#define GDIM 512
#define N_ITER 8
#define MAXDEG 64   // ELL width; Poisson(4)/Poisson(6) max over 120k rows << 64

typedef __attribute__((ext_vector_type(8))) short short8;   // 8 bf16 (4 VGPR) MFMA frag
typedef __attribute__((ext_vector_type(4))) float f32x4;    // MFMA acc frag

__device__ __forceinline__ ushort f2bf(float f) {           // fp32 -> bf16 RNE
    uint u = __float_as_uint(f);
    u = u + 0x7FFFu + ((u >> 16) & 1u);
    return (ushort)(u >> 16);
}
__device__ __forceinline__ float bf2f(ushort h) {
    return __uint_as_float(((uint)h) << 16);
}
// Truncation split: v = bf2f(hi)+bf2f(lo)+err, |err| <= 2^-16 |v| (4 VALU ops).
__device__ __forceinline__ void split2(float f, short& hi, short& lo) {
    uint u = __float_as_uint(f);
    hi = (short)(u >> 16);
    float r = f - __uint_as_float(u & 0xFFFF0000u);
    lo = (short)(__float_as_uint(r) >> 16);
}
__device__ __forceinline__ float sigmf(float x) { return 1.f / (1.f + __expf(-x)); }
__device__ __forceinline__ float tanh_f(float x) {
    float e = __expf(2.f * x);
    return 1.f - 2.f / (e + 1.f);
}
__device__ __forceinline__ f32x4 fzero4() {
    f32x4 v; v[0] = v[1] = v[2] = v[3] = 0.f; return v;
}

// ---------------------------------------------------------------------------
// ELL build: one atomic pass. cnt and ell must be zeroed.
// ---------------------------------------------------------------------------
__global__ __launch_bounds__(256) void fill_ell(
    const int* __restrict__ src, const int* __restrict__ dst,
    int* __restrict__ cnt, int* __restrict__ ell)
{
    int i = blockIdx.x * 256 + threadIdx.x;   // grid sized exactly N_EDGES/256
    int d = dst[i];
    int pos = atomicAdd(&cnt[d], 1);
    ell[(size_t)d * MAXDEG + pos] = src[i];
}

// ---------------------------------------------------------------------------
// Pack fp32 W[K,N] -> split-bf16 fragment-layout planes Ph, Pl (RNE; one-time).
// element = W[ks*32 + hi*8 + j][cc*16 + c], flat (((ks*NC+cc)*16+c)*4+hi)*8+j
// ---------------------------------------------------------------------------
__global__ __launch_bounds__(256) void pack_w2(const float* __restrict__ W,
                                               ushort* __restrict__ Ph,
                                               ushort* __restrict__ Pl, int K, int N)
{
    int NC = N / 16;
    int total = K * N;
    for (int o = blockIdx.x * 256 + threadIdx.x; o < total; o += gridDim.x * 256) {
        int j = o & 7, hi = (o >> 3) & 3, c = (o >> 5) & 15;
        int rest = o >> 9;
        int cc = rest % NC, ks = rest / NC;
        int row = ks * 32 + hi * 8 + j, col = cc * 16 + c;
        float v = W[(size_t)row * N + col];
        ushort h = f2bf(v);
        Ph[o] = h;
        Pl[o] = f2bf(v - bf2f(h));
    }
}

// ---------------------------------------------------------------------------
// Stage fp32 [nrows,128] rows into LDS as split-bf16 (hi plane at dst, lo at
// dst + nrows*128 elems). Row stride 256B, XOR-swizzled byte ^= (row&7)<<4.
// ---------------------------------------------------------------------------
__device__ __forceinline__ void stageA2(const float* __restrict__ src, int rowBase,
                                        ushort* dst, int tid, int nrows)
{
    const int planeB = nrows * 256;
    for (int idx = tid * 8; idx < nrows * 128; idx += 512 * 8) {
        int r = idx >> 7, k8 = idx & 127;
        const float* p = src + (size_t)(rowBase + r) * DIM + k8;
        float4 v0 = *(const float4*)p;
        float4 v1 = *(const float4*)(p + 4);
        float f[8] = {v0.x, v0.y, v0.z, v0.w, v1.x, v1.y, v1.z, v1.w};
        short8 hi8, lo8;
        #pragma unroll
        for (int j = 0; j < 8; ++j) {
            short h, l;
            split2(f[j], h, l);
            hi8[j] = h;
            lo8[j] = l;
        }
        int boff = r * 256 + ((k8 * 2) ^ ((r & 7) << 4));
        *(short8*)((char*)dst + boff) = hi8;
        *(short8*)((char*)dst + planeB + boff) = lo8;
    }
}

// A-frag: a[j] = A[mi*16 + (lane&15)][k0 + (lane>>4)*8 + j]  (swizzled LDS)
__device__ __forceinline__ short8 readA(const ushort* As, int mi, int k0, int lane)
{
    int r = mi * 16 + (lane & 15);
    int kb = (k0 * 2 + ((lane >> 4) << 4)) ^ ((r & 7) << 4);
    return *(const short8*)((const char*)As + r * 256 + kb);
}

// A-frag with row^1 (literal flip): tile row r of X1 == tile row r^1 of H.
__device__ __forceinline__ short8 readAf(const ushort* As, int mi, int k0, int lane)
{
    int r = (mi * 16 + (lane & 15)) ^ 1;
    int kb = (k0 * 2 + ((lane >> 4) << 4)) ^ ((r & 7) << 4);
    return *(const short8*)((const char*)As + r * 256 + kb);
}

__device__ __forceinline__ short8 readB(const ushort* P, int ks, int NC, int cc,
                                        int laneOff)
{
    return *(const short8*)((const char*)P + (((size_t)(ks * NC + cc)) << 10) + laneOff);
}

// 3-term split-bf16 MFMA: acc += (ah+al)(bh+bl), dropping lo*lo
#define MFMA3(acc, ah, al, bh, bl)                                              \
    do {                                                                        \
        acc = __builtin_amdgcn_mfma_f32_16x16x32_bf16(ah, bh, acc, 0, 0, 0);    \
        acc = __builtin_amdgcn_mfma_f32_16x16x32_bf16(ah, bl, acc, 0, 0, 0);    \
        acc = __builtin_amdgcn_mfma_f32_16x16x32_bf16(al, bh, acc, 0, 0, 0);    \
    } while (0)

// ---------------------------------------------------------------------------
// Fused 2-layer MLP: msg = relu(A@W1+b1)@W2+b2 (fp32 out). 64 rows/block,
// 512 thr (8 waves); wave wv owns output cols [16wv,16wv+16). Hidden in LDS
// as split-bf16.  (r8-proven configuration.)
// ---------------------------------------------------------------------------
__global__ __launch_bounds__(512, 4) void mlp_kernel(
    const float* __restrict__ A,
    const ushort* __restrict__ w1Ph, const ushort* __restrict__ w1Pl,
    const float* __restrict__ b1,
    const ushort* __restrict__ w2Ph, const ushort* __restrict__ w2Pl,
    const float* __restrict__ b2,
    float* __restrict__ msg)
{
    __shared__ __align__(16) ushort AsIn[2 * 64 * 128];
    __shared__ __align__(16) ushort AsHid[2 * 64 * 128];
    const int tid = threadIdx.x;
    const int wv = tid >> 6, lane = tid & 63;
    const int cl = lane & 15, hi = lane >> 4;
    const int rowBase = blockIdx.x * 64;
    const int laneOff = (cl * 4 + hi) * 16;
    const int col = wv * 16 + cl;

    stageA2(A, rowBase, AsIn, tid, 64);
    float b1c = b1[col], b2c = b2[col];
    __syncthreads();

    f32x4 acc[4];
    #pragma unroll
    for (int mi = 0; mi < 4; ++mi) acc[mi] = fzero4();
    #pragma unroll
    for (int ks = 0; ks < 4; ++ks) {
        short8 bh = readB(w1Ph, ks, 8, wv, laneOff);
        short8 bl = readB(w1Pl, ks, 8, wv, laneOff);
        #pragma unroll
        for (int mi = 0; mi < 4; ++mi) {
            short8 ah = readA(AsIn, mi, ks * 32, lane);
            short8 al = readA(AsIn + 64 * 128, mi, ks * 32, lane);
            MFMA3(acc[mi], ah, al, bh, bl);
        }
    }
    #pragma unroll
    for (int mi = 0; mi < 4; ++mi)
        #pragma unroll
        for (int q = 0; q < 4; ++q) {
            int row = mi * 16 + hi * 4 + q;
            float v = fmaxf(acc[mi][q] + b1c, 0.f);
            short h2, l2;
            split2(v, h2, l2);
            int boff = row * 256 + ((2 * col) ^ ((row & 7) << 4));
            *(short*)((char*)AsHid + boff) = h2;
            *(short*)((char*)AsHid + 64 * 256 + boff) = l2;
        }
    __syncthreads();

    f32x4 acc2[4];
    #pragma unroll
    for (int mi = 0; mi < 4; ++mi) acc2[mi] = fzero4();
    #pragma unroll
    for (int ks = 0; ks < 4; ++ks) {
        short8 bh = readB(w2Ph, ks, 8, wv, laneOff);
        short8 bl = readB(w2Pl, ks, 8, wv, laneOff);
        #pragma unroll
        for (int mi = 0; mi < 4; ++mi) {
            short8 ah = readA(AsHid, mi, ks * 32, lane);
            short8 al = readA(AsHid + 64 * 128, mi, ks * 32, lane);
            MFMA3(acc2[mi], ah, al, bh, bl);
        }
    }
    #pragma unroll
    for (int mi = 0; mi < 4; ++mi)
        #pragma unroll
        for (int q = 0; q < 4; ++q) {
            int row = mi * 16 + hi * 4 + q;
            msg[(size_t)(rowBase + row) * DIM + col] = acc2[mi][q] + b2c;
        }
}

// ---------------------------------------------------------------------------
// Fused ELL-gather + LN-LSTM cell. 64 rows/block, 512 threads = 8 waves.
// 64-row tile halves per-row weight-fragment L2 traffic vs r8's 32 (each
// readB B-fragment feeds 4 MFMA3s in registers). X1 (literal flip) read from
// AsH with row^1 (rowBase is a multiple of 64 -> pairs stay in-tile).
// LDS: 32+32+14.3 KB = 78.7 KB -> 2 blocks/CU.
// ---------------------------------------------------------------------------
template<int KX>   // 4 = clause, 8 = literal
__global__ __launch_bounds__(512, 2) void lstm_kernel(
    const float* __restrict__ msg, const int* __restrict__ cnt,
    const int* __restrict__ ell,
    const float* __restrict__ Hsrc,
    const ushort* __restrict__ wiPh, const ushort* __restrict__ wiPl,
    const ushort* __restrict__ whPh, const ushort* __restrict__ whPl,
    const float* __restrict__ g_ih, const float* __restrict__ b_ih,
    const float* __restrict__ g_hh, const float* __restrict__ b_hh,
    const float* __restrict__ g_c,  const float* __restrict__ b_c,
    float* __restrict__ c_state, float* __restrict__ h_out)
{
    __shared__ __align__(16) ushort AsX0[2 * 64 * 128];   // 32 KB
    __shared__ __align__(16) ushort AsH [2 * 64 * 128];   // 32 KB
    __shared__ float red4f[64 * 33];   // odd stride: conflict-free
    __shared__ float lnstf[64 * 4];
    __shared__ float red2f[64 * 17];
    __shared__ float lncf[64 * 2];

    const int tid = threadIdx.x;
    const int wv = tid >> 6, lane = tid & 63;
    const int cl = lane & 15, hi = lane >> 4;
    const int rowBase = blockIdx.x * 64;
    const int laneOff = (cl * 4 + hi) * 16;
    const int d = wv * 16 + cl;

    // linear stage first: static loads fire and overlap the gather below
    stageA2(Hsrc, rowBase, AsH, tid, 64);

    // ---- ELL gather -> X0 (8 threads/row, 16 dims each), 2-edge unroll ----
    {
        int r = tid >> 3;                  // 0..63
        int d16 = (tid & 7) << 4;          // 0,16,...,112
        int row = rowBase + r;
        int deg = cnt[row];
        const int* sl = ell + (size_t)row * MAXDEG;
        float a[16];
        #pragma unroll
        for (int j = 0; j < 16; ++j) a[j] = 0.f;
        for (int k = 0; k < deg; k += 2) {
            int i0 = sl[k], i1 = sl[k + 1];
            const float* m0 = msg + (size_t)i0 * DIM + d16;
            const float* m1 = msg + (size_t)i1 * DIM + d16;
            float4 p00 = *(const float4*)m0,        p01 = *(const float4*)(m0 + 4);
            float4 p02 = *(const float4*)(m0 + 8),  p03 = *(const float4*)(m0 + 12);
            float4 p10 = *(const float4*)m1,        p11 = *(const float4*)(m1 + 4);
            float4 p12 = *(const float4*)(m1 + 8),  p13 = *(const float4*)(m1 + 12);
            float w1 = (k + 1 < deg) ? 1.f : 0.f;
            a[0]  += p00.x; a[1]  += p00.y; a[2]  += p00.z; a[3]  += p00.w;
            a[4]  += p01.x; a[5]  += p01.y; a[6]  += p01.z; a[7]  += p01.w;
            a[8]  += p02.x; a[9]  += p02.y; a[10] += p02.z; a[11] += p02.w;
            a[12] += p03.x; a[13] += p03.y; a[14] += p03.z; a[15] += p03.w;
            a[0]  += w1 * p10.x; a[1]  += w1 * p10.y; a[2]  += w1 * p10.z; a[3]  += w1 * p10.w;
            a[4]  += w1 * p11.x; a[5]  += w1 * p11.y; a[6]  += w1 * p11.z; a[7]  += w1 * p11.w;
            a[8]  += w1 * p12.x; a[9]  += w1 * p12.y; a[10] += w1 * p12.z; a[11] += w1 * p12.w;
            a[12] += w1 * p13.x; a[13] += w1 * p13.y; a[14] += w1 * p13.z; a[15] += w1 * p13.w;
        }
        int sw = (r & 7) << 4;
        short8 hiA, loA, hiB, loB;
        #pragma unroll
        for (int j = 0; j < 8; ++j) {
            short h, l;
            split2(a[j], h, l);
            hiA[j] = h; loA[j] = l;
        }
        #pragma unroll
        for (int j = 0; j < 8; ++j) {
            short h, l;
            split2(a[8 + j], h, l);
            hiB[j] = h; loB[j] = l;
        }
        int b0 = r * 256 + ((d16 * 2) ^ sw);
        int b1 = r * 256 + (((d16 + 8) * 2) ^ sw);
        *(short8*)((char*)AsX0 + b0) = hiA;
        *(short8*)((char*)AsX0 + b1) = hiB;
        *(short8*)((char*)AsX0 + 64 * 256 + b0) = loA;
        *(short8*)((char*)AsX0 + 64 * 256 + b1) = loB;
    }

    float gih[4], bih[4], ghh[4], bhh[4];
    #pragma unroll
    for (int jb = 0; jb < 4; ++jb) {
        int col = jb * 128 + d;
        gih[jb] = g_ih[col]; bih[jb] = b_ih[col];
        ghh[jb] = g_hh[col]; bhh[jb] = b_hh[col];
    }
    const float gcv = g_c[d], bcv = b_c[d];
    __syncthreads();

    f32x4 xacc[4][4], hacc[4][4];   // [mi][jb]
    #pragma unroll
    for (int mi = 0; mi < 4; ++mi)
        #pragma unroll
        for (int jb = 0; jb < 4; ++jb) { xacc[mi][jb] = fzero4(); hacc[mi][jb] = fzero4(); }

    #pragma unroll
    for (int ks = 0; ks < KX; ++ks) {
        int k0 = (ks & 3) * 32;
        short8 axh[4], axl[4];
        #pragma unroll
        for (int mi = 0; mi < 4; ++mi) {
            if (KX == 8 && ks >= 4) {   // X1 tile = flip rows of the H tile
                axh[mi] = readAf(AsH, mi, k0, lane);
                axl[mi] = readAf(AsH + 64 * 128, mi, k0, lane);
            } else {
                axh[mi] = readA(AsX0, mi, k0, lane);
                axl[mi] = readA(AsX0 + 64 * 128, mi, k0, lane);
            }
        }
        #pragma unroll
        for (int jb = 0; jb < 4; ++jb) {
            short8 bh = readB(wiPh, ks, 32, jb * 8 + wv, laneOff);
            short8 bl = readB(wiPl, ks, 32, jb * 8 + wv, laneOff);
            #pragma unroll
            for (int mi = 0; mi < 4; ++mi) {
                MFMA3(xacc[mi][jb], axh[mi], axl[mi], bh, bl);
            }
        }
        if (ks < 4) {
            short8 ahh[4], ahl[4];
            #pragma unroll
            for (int mi = 0; mi < 4; ++mi) {
                ahh[mi] = readA(AsH, mi, k0, lane);
                ahl[mi] = readA(AsH + 64 * 128, mi, k0, lane);
            }
            #pragma unroll
            for (int jb = 0; jb < 4; ++jb) {
                short8 bh = readB(whPh, ks, 32, jb * 8 + wv, laneOff);
                short8 bl = readB(whPl, ks, 32, jb * 8 + wv, laneOff);
                #pragma unroll
                for (int mi = 0; mi < 4; ++mi) {
                    MFMA3(hacc[mi][jb], ahh[mi], ahl[mi], bh, bl);
                }
            }
        }
    }

    // ---- LN(512) stats for X and H ----
    #pragma unroll
    for (int mi = 0; mi < 4; ++mi)
        #pragma unroll
        for (int q = 0; q < 4; ++q) {
            float px = 0.f, pqx = 0.f, ph = 0.f, pqh = 0.f;
            #pragma unroll
            for (int jb = 0; jb < 4; ++jb) {
                float v = xacc[mi][jb][q]; px += v; pqx += v * v;
                float u = hacc[mi][jb][q]; ph += u; pqh += u * u;
            }
            #pragma unroll
            for (int m = 1; m < 16; m <<= 1) {
                px += __shfl_xor(px, m); pqx += __shfl_xor(pqx, m);
                ph += __shfl_xor(ph, m); pqh += __shfl_xor(pqh, m);
            }
            if (cl == 0) {
                int row = mi * 16 + hi * 4 + q;
                float* rp = red4f + row * 33 + wv * 4;
                rp[0] = px; rp[1] = pqx; rp[2] = ph; rp[3] = pqh;
            }
        }
    __syncthreads();
    if (tid < 64) {
        float sx = 0.f, qx = 0.f, sh = 0.f, qh = 0.f;
        const float* rp = red4f + tid * 33;
        for (int ww = 0; ww < 8; ++ww) {
            sx += rp[ww * 4 + 0]; qx += rp[ww * 4 + 1];
            sh += rp[ww * 4 + 2]; qh += rp[ww * 4 + 3];
        }
        const float inv = 1.f / 512.f;
        float mux = sx * inv, muh = sh * inv;
        lnstf[tid * 4 + 0] = mux;
        lnstf[tid * 4 + 1] = rsqrtf(qx * inv - mux * mux + 1e-5f);
        lnstf[tid * 4 + 2] = muh;
        lnstf[tid * 4 + 3] = rsqrtf(qh * inv - muh * muh + 1e-5f);
    }
    __syncthreads();

    float cn[4][4], og[4][4];
    #pragma unroll
    for (int mi = 0; mi < 4; ++mi)
        #pragma unroll
        for (int q = 0; q < 4; ++q) {
            int row = mi * 16 + hi * 4 + q;
            float mux = lnstf[row * 4 + 0], rx = lnstf[row * 4 + 1];
            float muh = lnstf[row * 4 + 2], rh = lnstf[row * 4 + 3];
            float g4[4];
            #pragma unroll
            for (int jb = 0; jb < 4; ++jb)
                g4[jb] = (xacc[mi][jb][q] - mux) * rx * gih[jb] + bih[jb]
                       + (hacc[mi][jb][q] - muh) * rh * ghh[jb] + bhh[jb];
            float cp = c_state[(size_t)(rowBase + row) * DIM + d];
            float cv = sigmf(g4[1]) * cp + sigmf(g4[0]) * tanh_f(g4[2]);
            cn[mi][q] = cv; og[mi][q] = g4[3];
            float sc = cv, qc = cv * cv;
            #pragma unroll
            for (int m = 1; m < 16; m <<= 1) {
                sc += __shfl_xor(sc, m); qc += __shfl_xor(qc, m);
            }
            if (cl == 0) {
                float* rp = red2f + row * 17 + wv * 2;
                rp[0] = sc; rp[1] = qc;
            }
        }
    __syncthreads();
    if (tid < 64) {
        float sc = 0.f, qc = 0.f;
        const float* rp = red2f + tid * 17;
        for (int ww = 0; ww < 8; ++ww) { sc += rp[ww * 2]; qc += rp[ww * 2 + 1]; }
        const float inv = 1.f / 128.f;
        float mu = sc * inv;
        lncf[tid * 2 + 0] = mu;
        lncf[tid * 2 + 1] = rsqrtf(qc * inv - mu * mu + 1e-5f);
    }
    __syncthreads();

    #pragma unroll
    for (int mi = 0; mi < 4; ++mi)
        #pragma unroll
        for (int q = 0; q < 4; ++q) {
            int row = mi * 16 + hi * 4 + q;
            size_t go = (size_t)(rowBase + row) * DIM + d;
            float cv = cn[mi][q];
            float hv = sigmf(og[mi][q]) *
                       tanh_f((cv - lncf[row * 2]) * lncf[row * 2 + 1] * gcv + bcv);
            c_state[go] = cv;
            h_out[go] = hv;
        }
}

// ---------------------------------------------------------------------------
extern "C" void kernel_launch(void* const* d_in, const int* in_sizes, int n_in,
                              void* d_out, int out_size, void* d_ws, size_t ws_size,
                              hipStream_t stream)
{
    const int*   l_edge  = (const int*)d_in[2];
    const int*   c_edge  = (const int*)d_in[3];
    const float* l_emb0  = (const float*)d_in[4];
    const float* c_emb0  = (const float*)d_in[5];
    const float* l2c_w1  = (const float*)d_in[6];
    const float* l2c_b1  = (const float*)d_in[7];
    const float* l2c_w2  = (const float*)d_in[8];
    const float* l2c_b2  = (const float*)d_in[9];
    const float* c2l_w1  = (const float*)d_in[10];
    const float* c2l_b1  = (const float*)d_in[11];
    const float* c2l_w2  = (const float*)d_in[12];
    const float* c2l_b2  = (const float*)d_in[13];
    const float* cu_wi   = (const float*)d_in[14];
    const float* cu_wh   = (const float*)d_in[15];
    const float* cu_g_ih = (const float*)d_in[16];
    const float* cu_b_ih = (const float*)d_in[17];
    const float* cu_g_hh = (const float*)d_in[18];
    const float* cu_b_hh = (const float*)d_in[19];
    const float* cu_g_c  = (const float*)d_in[20];
    const float* cu_b_c  = (const float*)d_in[21];
    const float* lu_wi   = (const float*)d_in[22];
    const float* lu_wh   = (const float*)d_in[23];
    const float* lu_g_ih = (const float*)d_in[24];
    const float* lu_b_ih = (const float*)d_in[25];
    const float* lu_g_hh = (const float*)d_in[26];
    const float* lu_b_hh = (const float*)d_in[27];
    const float* lu_g_c  = (const float*)d_in[28];
    const float* lu_b_c  = (const float*)d_in[29];

    float* out = (float*)d_out;
    float* l_slab = out;                              // [9, L, 128]
    float* c_slab = out + (size_t)9 * L_SIZE * DIM;   // [9, C, 128]

    // ---- workspace (~216 MB; identical footprint to verified round 8) ----
    char* wp = (char*)d_ws;
    float*  l_state = (float*)wp;  wp += (size_t)L_SIZE * DIM * 4;
    float*  c_state = (float*)wp;  wp += (size_t)C_SIZE * DIM * 4;
    float*  msg     = (float*)wp;  wp += (size_t)C_SIZE * DIM * 4;
    int* c_cnt = (int*)wp; wp += C_SIZE * 4;
    int* l_cnt = (int*)wp; wp += L_SIZE * 4;
    int* c_ell = (int*)wp; wp += (size_t)C_SIZE * MAXDEG * 4;   // 30.7 MB
    int* l_ell = (int*)wp; wp += (size_t)L_SIZE * MAXDEG * 4;   // 20.5 MB
    ushort* l2c_w1Ph = (ushort*)wp; wp += 128 * 128 * 2;
    ushort* l2c_w1Pl = (ushort*)wp; wp += 128 * 128 * 2;
    ushort* l2c_w2Ph = (ushort*)wp; wp += 128 * 128 * 2;
    ushort* l2c_w2Pl = (ushort*)wp; wp += 128 * 128 * 2;
    ushort* c2l_w1Ph = (ushort*)wp; wp += 128 * 128 * 2;
    ushort* c2l_w1Pl = (ushort*)wp; wp += 128 * 128 * 2;
    ushort* c2l_w2Ph = (ushort*)wp; wp += 128 * 128 * 2;
    ushort* c2l_w2Pl = (ushort*)wp; wp += 128 * 128 * 2;
    ushort* cu_wiPh  = (ushort*)wp; wp += 128 * 512 * 2;
    ushort* cu_wiPl  = (ushort*)wp; wp += 128 * 512 * 2;
    ushort* cu_whPh  = (ushort*)wp; wp += 128 * 512 * 2;
    ushort* cu_whPl  = (ushort*)wp; wp += 128 * 512 * 2;
    ushort* lu_wiPh  = (ushort*)wp; wp += 256 * 512 * 2;
    ushort* lu_wiPl  = (ushort*)wp; wp += 256 * 512 * 2;
    ushort* lu_whPh  = (ushort*)wp; wp += 128 * 512 * 2;
    ushort* lu_whPl  = (ushort*)wp; wp += 128 * 512 * 2;

    const int eb = N_EDGES / 256;

    // ELL build
    hipMemsetAsync(c_cnt, 0, C_SIZE * 4, stream);
    hipMemsetAsync(l_cnt, 0, L_SIZE * 4, stream);
    hipMemsetAsync(c_ell, 0, (size_t)C_SIZE * MAXDEG * 4, stream);
    hipMemsetAsync(l_ell, 0, (size_t)L_SIZE * MAXDEG * 4, stream);
    fill_ell<<<eb, 256, 0, stream>>>(l_edge, c_edge, c_cnt, c_ell);
    fill_ell<<<eb, 256, 0, stream>>>(c_edge, l_edge, l_cnt, l_ell);

    // pack weights to split-bf16 fragment layout
    pack_w2<<<64, 256, 0, stream>>>(l2c_w1, l2c_w1Ph, l2c_w1Pl, 128, 128);
    pack_w2<<<64, 256, 0, stream>>>(l2c_w2, l2c_w2Ph, l2c_w2Pl, 128, 128);
    pack_w2<<<64, 256, 0, stream>>>(c2l_w1, c2l_w1Ph, c2l_w1Pl, 128, 128);
    pack_w2<<<64, 256, 0, stream>>>(c2l_w2, c2l_w2Ph, c2l_w2Pl, 128, 128);
    pack_w2<<<256, 256, 0, stream>>>(cu_wi, cu_wiPh, cu_wiPl, 128, 512);
    pack_w2<<<256, 256, 0, stream>>>(cu_wh, cu_whPh, cu_whPl, 128, 512);
    pack_w2<<<512, 256, 0, stream>>>(lu_wi, lu_wiPh, lu_wiPl, 256, 512);
    pack_w2<<<256, 256, 0, stream>>>(lu_wh, lu_whPh, lu_whPl, 128, 512);

    hipMemcpyAsync(l_slab, l_emb0, (size_t)L_SIZE * DIM * sizeof(float),
                   hipMemcpyDeviceToDevice, stream);
    hipMemcpyAsync(c_slab, c_emb0, (size_t)C_SIZE * DIM * sizeof(float),
                   hipMemcpyDeviceToDevice, stream);
    hipMemsetAsync(l_state, 0, (size_t)L_SIZE * DIM * sizeof(float), stream);
    hipMemsetAsync(c_state, 0, (size_t)C_SIZE * DIM * sizeof(float), stream);

    for (int t = 0; t < N_ITER; ++t) {
        const float* le = l_slab + (size_t)t * L_SIZE * DIM;
        const float* ce = c_slab + (size_t)t * C_SIZE * DIM;
        float* le1 = l_slab + (size_t)(t + 1) * L_SIZE * DIM;
        float* ce1 = c_slab + (size_t)(t + 1) * C_SIZE * DIM;

        // ---- literal -> clause ----
        mlp_kernel<<<L_SIZE / 64, 512, 0, stream>>>(le, l2c_w1Ph, l2c_w1Pl, l2c_b1,
                                                    l2c_w2Ph, l2c_w2Pl, l2c_b2, msg);
        lstm_kernel<4><<<C_SIZE / 64, 512, 0, stream>>>(
            msg, c_cnt, c_ell, ce,
            cu_wiPh, cu_wiPl, cu_whPh, cu_whPl,
            cu_g_ih, cu_b_ih, cu_g_hh, cu_b_hh, cu_g_c, cu_b_c,
            c_state, ce1);

        // ---- clause -> literal ----
        mlp_kernel<<<C_SIZE / 64, 512, 0, stream>>>(ce1, c2l_w1Ph, c2l_w1Pl, c2l_b1,
                                                    c2l_w2Ph, c2l_w2Pl, c2l_b2, msg);
        lstm_kernel<8><<<L_SIZE / 64, 512, 0, stream>>>(
            msg, l_cnt, l_ell, le,
            lu_wiPh, lu_wiPl, lu_whPh, lu_whPl,
            lu_g_ih, lu_b_ih, lu_g_hh, lu_b_hh, lu_g_c, lu_b_c,
            l_state, le1);
    }
}

// Round 15
// 5269.118 us; speedup vs baseline: 1.1339x; 1.0117x over previous
//
#include <hip/hip_runtime.h>
#include <hip/hip_bf16.h>

#define L_SIZE 80000
#define C_SIZE 120000
#define N_EDGES 480000
#define DIM 128
#define GDIM 512
#define N_ITER 8
#define MAXDEG 64   // ELL width; Poisson(4)/Poisson(6) max over 120k rows << 64

typedef __attribute__((ext_vector_type(8))) short short8;   // 8 bf16 (4 VGPR) MFMA frag
typedef __attribute__((ext_vector_type(4))) float f32x4;    // MFMA acc frag

__device__ __forceinline__ ushort f2bf(float f) {           // fp32 -> bf16 RNE
    uint u = __float_as_uint(f);
    u = u + 0x7FFFu + ((u >> 16) & 1u);
    return (ushort)(u >> 16);
}
__device__ __forceinline__ float bf2f(ushort h) {
    return __uint_as_float(((uint)h) << 16);
}
__device__ __forceinline__ float sigmf(float x) { return 1.f / (1.f + __expf(-x)); }
__device__ __forceinline__ float tanh_f(float x) {
    float e = __expf(2.f * x);
    return 1.f - 2.f / (e + 1.f);
}
__device__ __forceinline__ f32x4 fzero4() {
    f32x4 v; v[0] = v[1] = v[2] = v[3] = 0.f; return v;
}

// ---------------------------------------------------------------------------
// ELL build: one atomic pass. cnt and ell must be zeroed (padded slots read
// row 0 — valid address — and are masked out in the gather).
// ---------------------------------------------------------------------------
__global__ __launch_bounds__(256) void fill_ell(
    const int* __restrict__ src, const int* __restrict__ dst,
    int* __restrict__ cnt, int* __restrict__ ell)
{
    int i = blockIdx.x * 256 + threadIdx.x;   // grid sized exactly N_EDGES/256
    int d = dst[i];
    int pos = atomicAdd(&cnt[d], 1);
    ell[(size_t)d * MAXDEG + pos] = src[i];
}

// ---------------------------------------------------------------------------
// Pack fp32 W[K,N] -> split-bf16 fragment-layout planes Ph, Pl (RNE; one-time).
// element = W[ks*32 + hi*8 + j][cc*16 + c], flat (((ks*NC+cc)*16+c)*4+hi)*8+j
// ---------------------------------------------------------------------------
__global__ __launch_bounds__(256) void pack_w2(const float* __restrict__ W,
                                               ushort* __restrict__ Ph,
                                               ushort* __restrict__ Pl, int K, int N)
{
    int NC = N / 16;
    int total = K * N;
    for (int o = blockIdx.x * 256 + threadIdx.x; o < total; o += gridDim.x * 256) {
        int j = o & 7, hi = (o >> 3) & 3, c = (o >> 5) & 15;
        int rest = o >> 9;
        int cc = rest % NC, ks = rest / NC;
        int row = ks * 32 + hi * 8 + j, col = cc * 16 + c;
        float v = W[(size_t)row * N + col];
        ushort h = f2bf(v);
        Ph[o] = h;
        Pl[o] = f2bf(v - bf2f(h));
    }
}

// ---------------------------------------------------------------------------
// Stage fp32 [nrows,128] rows (rowBase..)^rowXor into LDS as split-bf16:
// hi plane at dst, lo plane at dst + nrows*128 elems. Row stride 256B,
// XOR-swizzled byte ^= (row&7)<<4 (conflict-free ds_read_b128 frag reads).
// ---------------------------------------------------------------------------
__device__ __forceinline__ void stageA2(const float* __restrict__ src, int rowBase,
                                        int rowXor, ushort* dst, int tid, int nrows)
{
    const int planeB = nrows * 256;
    for (int idx = tid * 8; idx < nrows * 128; idx += 512 * 8) {
        int r = idx >> 7, k8 = idx & 127;
        const float* p = src + (size_t)((rowBase + r) ^ rowXor) * DIM + k8;
        float4 v0 = *(const float4*)p;
        float4 v1 = *(const float4*)(p + 4);
        float f[8] = {v0.x, v0.y, v0.z, v0.w, v1.x, v1.y, v1.z, v1.w};
        short8 hi8, lo8;
        #pragma unroll
        for (int j = 0; j < 8; ++j) {
            ushort h = f2bf(f[j]);
            hi8[j] = (short)h;
            lo8[j] = (short)f2bf(f[j] - bf2f(h));
        }
        int boff = r * 256 + ((k8 * 2) ^ ((r & 7) << 4));
        *(short8*)((char*)dst + boff) = hi8;
        *(short8*)((char*)dst + planeB + boff) = lo8;
    }
}

// A-frag: a[j] = A[mi*16 + (lane&15)][k0 + (lane>>4)*8 + j]  (swizzled LDS)
__device__ __forceinline__ short8 readA(const ushort* As, int mi, int k0, int lane)
{
    int r = mi * 16 + (lane & 15);
    int kb = (k0 * 2 + ((lane >> 4) << 4)) ^ ((r & 7) << 4);
    return *(const short8*)((const char*)As + r * 256 + kb);
}

__device__ __forceinline__ short8 readB(const ushort* P, int ks, int NC, int cc,
                                        int laneOff)
{
    return *(const short8*)((const char*)P + (((size_t)(ks * NC + cc)) << 10) + laneOff);
}

// 3-term split-bf16 MFMA: acc += (ah+al)(bh+bl), dropping lo*lo
#define MFMA3(acc, ah, al, bh, bl)                                              \
    do {                                                                        \
        acc = __builtin_amdgcn_mfma_f32_16x16x32_bf16(ah, bh, acc, 0, 0, 0);    \
        acc = __builtin_amdgcn_mfma_f32_16x16x32_bf16(ah, bl, acc, 0, 0, 0);    \
        acc = __builtin_amdgcn_mfma_f32_16x16x32_bf16(al, bh, acc, 0, 0, 0);    \
    } while (0)

// ---------------------------------------------------------------------------
// Fused 2-layer MLP: msg = relu(A@W1+b1)@W2+b2 (fp32 out). 64 rows/block,
// 512 thr (8 waves); wave wv owns output cols [16wv,16wv+16). Hidden in LDS
// as split-bf16.
// ---------------------------------------------------------------------------
__global__ __launch_bounds__(512, 4) void mlp_kernel(
    const float* __restrict__ A,
    const ushort* __restrict__ w1Ph, const ushort* __restrict__ w1Pl,
    const float* __restrict__ b1,
    const ushort* __restrict__ w2Ph, const ushort* __restrict__ w2Pl,
    const float* __restrict__ b2,
    float* __restrict__ msg)
{
    __shared__ __align__(16) ushort AsIn[2 * 64 * 128];
    __shared__ __align__(16) ushort AsHid[2 * 64 * 128];
    const int tid = threadIdx.x;
    const int wv = tid >> 6, lane = tid & 63;
    const int cl = lane & 15, hi = lane >> 4;
    const int rowBase = blockIdx.x * 64;
    const int laneOff = (cl * 4 + hi) * 16;
    const int col = wv * 16 + cl;

    stageA2(A, rowBase, 0, AsIn, tid, 64);
    float b1c = b1[col], b2c = b2[col];
    __syncthreads();

    f32x4 acc[4];
    #pragma unroll
    for (int mi = 0; mi < 4; ++mi) acc[mi] = fzero4();
    #pragma unroll
    for (int ks = 0; ks < 4; ++ks) {
        short8 bh = readB(w1Ph, ks, 8, wv, laneOff);
        short8 bl = readB(w1Pl, ks, 8, wv, laneOff);
        #pragma unroll
        for (int mi = 0; mi < 4; ++mi) {
            short8 ah = readA(AsIn, mi, ks * 32, lane);
            short8 al = readA(AsIn + 64 * 128, mi, ks * 32, lane);
            MFMA3(acc[mi], ah, al, bh, bl);
        }
    }
    #pragma unroll
    for (int mi = 0; mi < 4; ++mi)
        #pragma unroll
        for (int q = 0; q < 4; ++q) {
            int row = mi * 16 + hi * 4 + q;
            float v = fmaxf(acc[mi][q] + b1c, 0.f);
            ushort h = f2bf(v);
            int boff = row * 256 + ((2 * col) ^ ((row & 7) << 4));
            *(ushort*)((char*)AsHid + boff) = h;
            *(ushort*)((char*)AsHid + 64 * 256 + boff) = f2bf(v - bf2f(h));
        }
    __syncthreads();

    f32x4 acc2[4];
    #pragma unroll
    for (int mi = 0; mi < 4; ++mi) acc2[mi] = fzero4();
    #pragma unroll
    for (int ks = 0; ks < 4; ++ks) {
        short8 bh = readB(w2Ph, ks, 8, wv, laneOff);
        short8 bl = readB(w2Pl, ks, 8, wv, laneOff);
        #pragma unroll
        for (int mi = 0; mi < 4; ++mi) {
            short8 ah = readA(AsHid, mi, ks * 32, lane);
            short8 al = readA(AsHid + 64 * 128, mi, ks * 32, lane);
            MFMA3(acc2[mi], ah, al, bh, bl);
        }
    }
    #pragma unroll
    for (int mi = 0; mi < 4; ++mi)
        #pragma unroll
        for (int q = 0; q < 4; ++q) {
            int row = mi * 16 + hi * 4 + q;
            msg[(size_t)(rowBase + row) * DIM + col] = acc2[mi][q] + b2c;
        }
}

// ---------------------------------------------------------------------------
// Fused ELL-gather + LN-LSTM cell. 32 rows/block, 512 threads = 8 waves.
// Linear stages (H, X1) issue FIRST so their loads overlap the gather chain;
// gather is 4-edge unrolled (8 independent float4 loads in flight) with
// per-edge masks (padded slots point at row 0, masked out).
// ---------------------------------------------------------------------------
template<int KX>   // 4 = clause, 8 = literal
__global__ __launch_bounds__(512, 4) void lstm_kernel(
    const float* __restrict__ msg, const int* __restrict__ cnt,
    const int* __restrict__ ell,
    const float* __restrict__ X1src, const float* __restrict__ Hsrc,
    const ushort* __restrict__ wiPh, const ushort* __restrict__ wiPl,
    const ushort* __restrict__ whPh, const ushort* __restrict__ whPl,
    const float* __restrict__ g_ih, const float* __restrict__ b_ih,
    const float* __restrict__ g_hh, const float* __restrict__ b_hh,
    const float* __restrict__ g_c,  const float* __restrict__ b_c,
    float* __restrict__ c_state, float* __restrict__ h_out)
{
    __shared__ __align__(16) ushort AsX0[2 * 32 * 128];
    __shared__ __align__(16) ushort AsX1[KX == 8 ? 2 * 32 * 128 : 8];
    __shared__ __align__(16) ushort AsH [2 * 32 * 128];
    __shared__ float red4f[32 * 33];   // odd stride: conflict-free
    __shared__ float lnstf[32 * 4];
    __shared__ float red2f[32 * 17];
    __shared__ float lncf[32 * 2];

    const int tid = threadIdx.x;
    const int wv = tid >> 6, lane = tid & 63;
    const int cl = lane & 15, hi = lane >> 4;
    const int rowBase = blockIdx.x * 32;
    const int laneOff = (cl * 4 + hi) * 16;
    const int d = wv * 16 + cl;

    // linear stages first: static loads fire and overlap the gather below
    stageA2(Hsrc, rowBase, 0, AsH, tid, 32);
    if (KX == 8) stageA2(X1src, rowBase, 1, AsX1, tid, 32);

    // ---- ELL gather -> X0 (16 threads/row, 8 dims each), 4-edge unrolled ----
    {
        int r = tid >> 4;
        int d8 = (tid & 15) << 3;
        int row = rowBase + r;
        int deg = cnt[row];
        const int* sl = ell + (size_t)row * MAXDEG;
        float a0=0,a1=0,a2=0,a3=0,a4=0,a5=0,a6=0,a7=0;
        for (int k = 0; k < deg; k += 4) {
            int i0 = sl[k], i1 = sl[k+1], i2 = sl[k+2], i3 = sl[k+3];
            const float* m0 = msg + (size_t)i0 * DIM + d8;
            const float* m1 = msg + (size_t)i1 * DIM + d8;
            const float* m2 = msg + (size_t)i2 * DIM + d8;
            const float* m3 = msg + (size_t)i3 * DIM + d8;
            float4 p00 = *(const float4*)m0,       p01 = *(const float4*)(m0 + 4);
            float4 p10 = *(const float4*)m1,       p11 = *(const float4*)(m1 + 4);
            float4 p20 = *(const float4*)m2,       p21 = *(const float4*)(m2 + 4);
            float4 p30 = *(const float4*)m3,       p31 = *(const float4*)(m3 + 4);
            float w1 = (k + 1 < deg) ? 1.f : 0.f;
            float w2 = (k + 2 < deg) ? 1.f : 0.f;
            float w3 = (k + 3 < deg) ? 1.f : 0.f;
            a0 += p00.x; a1 += p00.y; a2 += p00.z; a3 += p00.w;
            a4 += p01.x; a5 += p01.y; a6 += p01.z; a7 += p01.w;
            a0 += w1 * p10.x; a1 += w1 * p10.y; a2 += w1 * p10.z; a3 += w1 * p10.w;
            a4 += w1 * p11.x; a5 += w1 * p11.y; a6 += w1 * p11.z; a7 += w1 * p11.w;
            a0 += w2 * p20.x; a1 += w2 * p20.y; a2 += w2 * p20.z; a3 += w2 * p20.w;
            a4 += w2 * p21.x; a5 += w2 * p21.y; a6 += w2 * p21.z; a7 += w2 * p21.w;
            a0 += w3 * p30.x; a1 += w3 * p30.y; a2 += w3 * p30.z; a3 += w3 * p30.w;
            a4 += w3 * p31.x; a5 += w3 * p31.y; a6 += w3 * p31.z; a7 += w3 * p31.w;
        }
        float f[8] = {a0,a1,a2,a3,a4,a5,a6,a7};
        short8 hi8, lo8;
        #pragma unroll
        for (int j = 0; j < 8; ++j) {
            ushort h = f2bf(f[j]);
            hi8[j] = (short)h;
            lo8[j] = (short)f2bf(f[j] - bf2f(h));
        }
        int boff = r * 256 + ((d8 * 2) ^ ((r & 7) << 4));
        *(short8*)((char*)AsX0 + boff) = hi8;
        *(short8*)((char*)AsX0 + 32 * 256 + boff) = lo8;
    }

    float gih[4], bih[4], ghh[4], bhh[4];
    #pragma unroll
    for (int jb = 0; jb < 4; ++jb) {
        int col = jb * 128 + d;
        gih[jb] = g_ih[col]; bih[jb] = b_ih[col];
        ghh[jb] = g_hh[col]; bhh[jb] = b_hh[col];
    }
    const float gcv = g_c[d], bcv = b_c[d];
    __syncthreads();

    f32x4 xacc[2][4], hacc[2][4];
    #pragma unroll
    for (int mi = 0; mi < 2; ++mi)
        #pragma unroll
        for (int jb = 0; jb < 4; ++jb) { xacc[mi][jb] = fzero4(); hacc[mi][jb] = fzero4(); }

    #pragma unroll
    for (int ks = 0; ks < KX; ++ks) {
        const ushort* AX = (KX == 8 && ks >= 4) ? AsX1 : AsX0;
        int k0 = (ks & 3) * 32;
        short8 axh0 = readA(AX, 0, k0, lane);
        short8 axl0 = readA(AX + 32 * 128, 0, k0, lane);
        short8 axh1 = readA(AX, 1, k0, lane);
        short8 axl1 = readA(AX + 32 * 128, 1, k0, lane);
        #pragma unroll
        for (int jb = 0; jb < 4; ++jb) {
            short8 bh = readB(wiPh, ks, 32, jb * 8 + wv, laneOff);
            short8 bl = readB(wiPl, ks, 32, jb * 8 + wv, laneOff);
            MFMA3(xacc[0][jb], axh0, axl0, bh, bl);
            MFMA3(xacc[1][jb], axh1, axl1, bh, bl);
        }
        if (ks < 4) {
            short8 ahh0 = readA(AsH, 0, k0, lane);
            short8 ahl0 = readA(AsH + 32 * 128, 0, k0, lane);
            short8 ahh1 = readA(AsH, 1, k0, lane);
            short8 ahl1 = readA(AsH + 32 * 128, 1, k0, lane);
            #pragma unroll
            for (int jb = 0; jb < 4; ++jb) {
                short8 bh = readB(whPh, ks, 32, jb * 8 + wv, laneOff);
                short8 bl = readB(whPl, ks, 32, jb * 8 + wv, laneOff);
                MFMA3(hacc[0][jb], ahh0, ahl0, bh, bl);
                MFMA3(hacc[1][jb], ahh1, ahl1, bh, bl);
            }
        }
    }

    // ---- LN(512) stats for X and H ----
    #pragma unroll
    for (int mi = 0; mi < 2; ++mi)
        #pragma unroll
        for (int q = 0; q < 4; ++q) {
            float px = 0.f, pqx = 0.f, ph = 0.f, pqh = 0.f;
            #pragma unroll
            for (int jb = 0; jb < 4; ++jb) {
                float v = xacc[mi][jb][q]; px += v; pqx += v * v;
                float u = hacc[mi][jb][q]; ph += u; pqh += u * u;
            }
            #pragma unroll
            for (int m = 1; m < 16; m <<= 1) {
                px += __shfl_xor(px, m); pqx += __shfl_xor(pqx, m);
                ph += __shfl_xor(ph, m); pqh += __shfl_xor(pqh, m);
            }
            if (cl == 0) {
                int row = mi * 16 + hi * 4 + q;
                float* rp = red4f + row * 33 + wv * 4;
                rp[0] = px; rp[1] = pqx; rp[2] = ph; rp[3] = pqh;
            }
        }
    __syncthreads();
    if (tid < 32) {
        float sx = 0.f, qx = 0.f, sh = 0.f, qh = 0.f;
        const float* rp = red4f + tid * 33;
        for (int ww = 0; ww < 8; ++ww) {
            sx += rp[ww * 4 + 0]; qx += rp[ww * 4 + 1];
            sh += rp[ww * 4 + 2]; qh += rp[ww * 4 + 3];
        }
        const float inv = 1.f / 512.f;
        float mux = sx * inv, muh = sh * inv;
        lnstf[tid * 4 + 0] = mux;
        lnstf[tid * 4 + 1] = rsqrtf(qx * inv - mux * mux + 1e-5f);
        lnstf[tid * 4 + 2] = muh;
        lnstf[tid * 4 + 3] = rsqrtf(qh * inv - muh * muh + 1e-5f);
    }
    __syncthreads();

    float cn[2][4], og[2][4];
    #pragma unroll
    for (int mi = 0; mi < 2; ++mi)
        #pragma unroll
        for (int q = 0; q < 4; ++q) {
            int row = mi * 16 + hi * 4 + q;
            float mux = lnstf[row * 4 + 0], rx = lnstf[row * 4 + 1];
            float muh = lnstf[row * 4 + 2], rh = lnstf[row * 4 + 3];
            float g4[4];
            #pragma unroll
            for (int jb = 0; jb < 4; ++jb)
                g4[jb] = (xacc[mi][jb][q] - mux) * rx * gih[jb] + bih[jb]
                       + (hacc[mi][jb][q] - muh) * rh * ghh[jb] + bhh[jb];
            float cp = c_state[(size_t)(rowBase + row) * DIM + d];
            float cv = sigmf(g4[1]) * cp + sigmf(g4[0]) * tanh_f(g4[2]);
            cn[mi][q] = cv; og[mi][q] = g4[3];
            float sc = cv, qc = cv * cv;
            #pragma unroll
            for (int m = 1; m < 16; m <<= 1) {
                sc += __shfl_xor(sc, m); qc += __shfl_xor(qc, m);
            }
            if (cl == 0) {
                float* rp = red2f + row * 17 + wv * 2;
                rp[0] = sc; rp[1] = qc;
            }
        }
    __syncthreads();
    if (tid < 32) {
        float sc = 0.f, qc = 0.f;
        const float* rp = red2f + tid * 17;
        for (int ww = 0; ww < 8; ++ww) { sc += rp[ww * 2]; qc += rp[ww * 2 + 1]; }
        const float inv = 1.f / 128.f;
        float mu = sc * inv;
        lncf[tid * 2 + 0] = mu;
        lncf[tid * 2 + 1] = rsqrtf(qc * inv - mu * mu + 1e-5f);
    }
    __syncthreads();

    #pragma unroll
    for (int mi = 0; mi < 2; ++mi)
        #pragma unroll
        for (int q = 0; q < 4; ++q) {
            int row = mi * 16 + hi * 4 + q;
            size_t go = (size_t)(rowBase + row) * DIM + d;
            float cv = cn[mi][q];
            float hv = sigmf(og[mi][q]) *
                       tanh_f((cv - lncf[row * 2]) * lncf[row * 2 + 1] * gcv + bcv);
            c_state[go] = cv;
            h_out[go] = hv;
        }
}

// ---------------------------------------------------------------------------
extern "C" void kernel_launch(void* const* d_in, const int* in_sizes, int n_in,
                              void* d_out, int out_size, void* d_ws, size_t ws_size,
                              hipStream_t stream)
{
    const int*   l_edge  = (const int*)d_in[2];
    const int*   c_edge  = (const int*)d_in[3];
    const float* l_emb0  = (const float*)d_in[4];
    const float* c_emb0  = (const float*)d_in[5];
    const float* l2c_w1  = (const float*)d_in[6];
    const float* l2c_b1  = (const float*)d_in[7];
    const float* l2c_w2  = (const float*)d_in[8];
    const float* l2c_b2  = (const float*)d_in[9];
    const float* c2l_w1  = (const float*)d_in[10];
    const float* c2l_b1  = (const float*)d_in[11];
    const float* c2l_w2  = (const float*)d_in[12];
    const float* c2l_b2  = (const float*)d_in[13];
    const float* cu_wi   = (const float*)d_in[14];
    const float* cu_wh   = (const float*)d_in[15];
    const float* cu_g_ih = (const float*)d_in[16];
    const float* cu_b_ih = (const float*)d_in[17];
    const float* cu_g_hh = (const float*)d_in[18];
    const float* cu_b_hh = (const float*)d_in[19];
    const float* cu_g_c  = (const float*)d_in[20];
    const float* cu_b_c  = (const float*)d_in[21];
    const float* lu_wi   = (const float*)d_in[22];
    const float* lu_wh   = (const float*)d_in[23];
    const float* lu_g_ih = (const float*)d_in[24];
    const float* lu_b_ih = (const float*)d_in[25];
    const float* lu_g_hh = (const float*)d_in[26];
    const float* lu_b_hh = (const float*)d_in[27];
    const float* lu_g_c  = (const float*)d_in[28];
    const float* lu_b_c  = (const float*)d_in[29];

    float* out = (float*)d_out;
    float* l_slab = out;                              // [9, L, 128]
    float* c_slab = out + (size_t)9 * L_SIZE * DIM;   // [9, C, 128]

    // ---- workspace (~216 MB) ----
    char* wp = (char*)d_ws;
    float*  l_state = (float*)wp;  wp += (size_t)L_SIZE * DIM * 4;
    float*  c_state = (float*)wp;  wp += (size_t)C_SIZE * DIM * 4;
    float*  msg     = (float*)wp;  wp += (size_t)C_SIZE * DIM * 4;
    int* c_cnt = (int*)wp; wp += C_SIZE * 4;
    int* l_cnt = (int*)wp; wp += L_SIZE * 4;
    int* c_ell = (int*)wp; wp += (size_t)C_SIZE * MAXDEG * 4;   // 30.7 MB
    int* l_ell = (int*)wp; wp += (size_t)L_SIZE * MAXDEG * 4;   // 20.5 MB
    ushort* l2c_w1Ph = (ushort*)wp; wp += 128 * 128 * 2;
    ushort* l2c_w1Pl = (ushort*)wp; wp += 128 * 128 * 2;
    ushort* l2c_w2Ph = (ushort*)wp; wp += 128 * 128 * 2;
    ushort* l2c_w2Pl = (ushort*)wp; wp += 128 * 128 * 2;
    ushort* c2l_w1Ph = (ushort*)wp; wp += 128 * 128 * 2;
    ushort* c2l_w1Pl = (ushort*)wp; wp += 128 * 128 * 2;
    ushort* c2l_w2Ph = (ushort*)wp; wp += 128 * 128 * 2;
    ushort* c2l_w2Pl = (ushort*)wp; wp += 128 * 128 * 2;
    ushort* cu_wiPh  = (ushort*)wp; wp += 128 * 512 * 2;
    ushort* cu_wiPl  = (ushort*)wp; wp += 128 * 512 * 2;
    ushort* cu_whPh  = (ushort*)wp; wp += 128 * 512 * 2;
    ushort* cu_whPl  = (ushort*)wp; wp += 128 * 512 * 2;
    ushort* lu_wiPh  = (ushort*)wp; wp += 256 * 512 * 2;
    ushort* lu_wiPl  = (ushort*)wp; wp += 256 * 512 * 2;
    ushort* lu_whPh  = (ushort*)wp; wp += 128 * 512 * 2;
    ushort* lu_whPl  = (ushort*)wp; wp += 128 * 512 * 2;

    const int eb = N_EDGES / 256;

    // ELL build
    hipMemsetAsync(c_cnt, 0, C_SIZE * 4, stream);
    hipMemsetAsync(l_cnt, 0, L_SIZE * 4, stream);
    hipMemsetAsync(c_ell, 0, (size_t)C_SIZE * MAXDEG * 4, stream);
    hipMemsetAsync(l_ell, 0, (size_t)L_SIZE * MAXDEG * 4, stream);
    fill_ell<<<eb, 256, 0, stream>>>(l_edge, c_edge, c_cnt, c_ell);
    fill_ell<<<eb, 256, 0, stream>>>(c_edge, l_edge, l_cnt, l_ell);

    // pack weights to split-bf16 fragment layout
    pack_w2<<<64, 256, 0, stream>>>(l2c_w1, l2c_w1Ph, l2c_w1Pl, 128, 128);
    pack_w2<<<64, 256, 0, stream>>>(l2c_w2, l2c_w2Ph, l2c_w2Pl, 128, 128);
    pack_w2<<<64, 256, 0, stream>>>(c2l_w1, c2l_w1Ph, c2l_w1Pl, 128, 128);
    pack_w2<<<64, 256, 0, stream>>>(c2l_w2, c2l_w2Ph, c2l_w2Pl, 128, 128);
    pack_w2<<<256, 256, 0, stream>>>(cu_wi, cu_wiPh, cu_wiPl, 128, 512);
    pack_w2<<<256, 256, 0, stream>>>(cu_wh, cu_whPh, cu_whPl, 128, 512);
    pack_w2<<<512, 256, 0, stream>>>(lu_wi, lu_wiPh, lu_wiPl, 256, 512);
    pack_w2<<<256, 256, 0, stream>>>(lu_wh, lu_whPh, lu_whPl, 128, 512);

    hipMemcpyAsync(l_slab, l_emb0, (size_t)L_SIZE * DIM * sizeof(float),
                   hipMemcpyDeviceToDevice, stream);
    hipMemcpyAsync(c_slab, c_emb0, (size_t)C_SIZE * DIM * sizeof(float),
                   hipMemcpyDeviceToDevice, stream);
    hipMemsetAsync(l_state, 0, (size_t)L_SIZE * DIM * sizeof(float), stream);
    hipMemsetAsync(c_state, 0, (size_t)C_SIZE * DIM * sizeof(float), stream);

    for (int t = 0; t < N_ITER; ++t) {
        const float* le = l_slab + (size_t)t * L_SIZE * DIM;
        const float* ce = c_slab + (size_t)t * C_SIZE * DIM;
        float* le1 = l_slab + (size_t)(t + 1) * L_SIZE * DIM;
        float* ce1 = c_slab + (size_t)(t + 1) * C_SIZE * DIM;

        // ---- literal -> clause ----
        mlp_kernel<<<L_SIZE / 64, 512, 0, stream>>>(le, l2c_w1Ph, l2c_w1Pl, l2c_b1,
                                                    l2c_w2Ph, l2c_w2Pl, l2c_b2, msg);
        lstm_kernel<4><<<C_SIZE / 32, 512, 0, stream>>>(
            msg, c_cnt, c_ell, nullptr, ce,
            cu_wiPh, cu_wiPl, cu_whPh, cu_whPl,
            cu_g_ih, cu_b_ih, cu_g_hh, cu_b_hh, cu_g_c, cu_b_c,
            c_state, ce1);

        // ---- clause -> literal ----
        mlp_kernel<<<C_SIZE / 64, 512, 0, stream>>>(ce1, c2l_w1Ph, c2l_w1Pl, c2l_b1,
                                                    c2l_w2Ph, c2l_w2Pl, c2l_b2, msg);
        lstm_kernel<8><<<L_SIZE / 32, 512, 0, stream>>>(
            msg, l_cnt, l_ell, le, le,
            lu_wiPh, lu_wiPl, lu_whPh, lu_whPl,
            lu_g_ih, lu_b_ih, lu_g_hh, lu_b_hh, lu_g_c, lu_b_c,
            l_state, le1);
    }
}